// Round 1
// baseline (143.485 us; speedup 1.0000x reference)
//
#include <hip/hip_runtime.h>
#include <cfloat>
#include <math.h>

#define B_ 4
#define L_ 1024
#define D_ 8
#define OUT_ 224
#define NPIX (B_ * 2 * D_ * OUT_ * OUT_)   // 3211264
#define PI_F 3.14159265358979323846f

// reference: x_norm = ((x-lo)/(rng+1e-8))*2 - 1 (or 0 if rng<1e-8), clipped to [-1+1e-6, 1-1e-6]
__device__ __forceinline__ float clipnorm(float v, float lo, float inv2, int degen) {
    float xn = degen ? -1.0f : ((v - lo) * inv2 - 1.0f);
    return fminf(fmaxf(xn, -1.0f + 1e-6f), 1.0f - 1e-6f);
}

// One block per (b,d). 1024 threads. Computes gaf min/max and rp quantile threshold.
__global__ __launch_bounds__(1024) void k_stats(const float* __restrict__ x,
                                                float* __restrict__ ws) {
    __shared__ float t[L_];      // sorted series values
    __shared__ float csort[L_];  // clipped-normalized at sorted positions
    __shared__ float ssort[L_];  // sqrt(1-c^2)
    __shared__ float w[L_];      // theta = acos(c), descending
    __shared__ float redf[40];
    __shared__ unsigned redc[20];

    const int tid  = threadIdx.x;
    const int lane = tid & 63, wave = tid >> 6;  // 16 waves
    const int blk  = blockIdx.x;
    const int b = blk >> 3, d = blk & 7;

    // ---- global min/max over all of x (redundant per block; x = 128KB, L2-hot) ----
    float lo = FLT_MAX, hi = -FLT_MAX;
    for (int i = tid; i < B_ * L_ * D_; i += 1024) {
        float v = x[i];
        lo = fminf(lo, v); hi = fmaxf(hi, v);
    }
#pragma unroll
    for (int off = 32; off; off >>= 1) {
        lo = fminf(lo, __shfl_down(lo, off));
        hi = fmaxf(hi, __shfl_down(hi, off));
    }
    if (lane == 0) { redf[wave] = lo; redf[16 + wave] = hi; }
    __syncthreads();
    if (tid == 0) {
        float l = redf[0], h = redf[16];
        for (int ww = 1; ww < 16; ww++) { l = fminf(l, redf[ww]); h = fmaxf(h, redf[16 + ww]); }
        redf[32] = l; redf[33] = h;
        if (blk == 0) { ws[0] = l; ws[1] = h; }
    }
    __syncthreads();
    lo = redf[32]; hi = redf[33];
    const float rng  = hi - lo;
    const int degen  = rng < 1e-8f;
    const float inv2 = 2.0f / (rng + 1e-8f);

    // ---- load series (strided by D) ----
    t[tid] = x[(b * L_ + tid) * D_ + d];
    __syncthreads();

    // ---- bitonic sort t ascending ----
    for (int k = 2; k <= L_; k <<= 1) {
        for (int j = k >> 1; j > 0; j >>= 1) {
            __syncthreads();
            int i = tid;
            int p = i ^ j;
            if (p > i) {
                float a = t[i], c2 = t[p];
                bool up = ((i & k) == 0);
                if ((a > c2) == up) { t[i] = c2; t[p] = a; }
            }
        }
    }
    __syncthreads();

    // ---- derived arrays at sorted positions ----
    {
        float c = clipnorm(t[tid], lo, inv2, degen);
        csort[tid] = c;
        ssort[tid] = sqrtf(fmaxf(0.0f, 1.0f - c * c));
        w[tid]     = acosf(c);   // descending in tid (t ascending -> c ascending -> theta descending)
    }
    __syncthreads();

    // ---- GAF min/max: cos(wi+wj). Extremes at sums nearest 0, pi, 2pi.
    // For row i, sums wi+w[j] are descending in j; candidates: j=0 (largest sum),
    // j=L-1 (smallest sum), and the pi-crossing pair (jstar, jstar+1).
    {
        float wi = w[tid];
        int jstar = -1;
        if (wi + w[0] >= PI_F) {
            int a = 0, bh = L_ - 1;
            while (a < bh) { int m = (a + bh + 1) >> 1; if (wi + w[m] >= PI_F) a = m; else bh = m - 1; }
            jstar = a;
        }
        float ci = csort[tid], si = ssort[tid];
        float mn = FLT_MAX, mx = -FLT_MAX;
        int cand0 = 0, cand1 = L_ - 1, cand2 = jstar, cand3 = jstar + 1;
        int cands[4] = {cand0, cand1, cand2, cand3};
#pragma unroll
        for (int q = 0; q < 4; q++) {
            int j = cands[q];
            if (j >= 0 && j < L_) {
                float g = ci * csort[j] - si * ssort[j];
                mn = fminf(mn, g); mx = fmaxf(mx, g);
            }
        }
#pragma unroll
        for (int off = 32; off; off >>= 1) {
            mn = fminf(mn, __shfl_down(mn, off));
            mx = fmaxf(mx, __shfl_down(mx, off));
        }
        if (lane == 0) { redf[wave] = mn; redf[16 + wave] = mx; }
        __syncthreads();
        if (tid == 0) {
            float l = redf[0], h = redf[16];
            for (int ww = 1; ww < 16; ww++) { l = fminf(l, redf[ww]); h = fmaxf(h, redf[16 + ww]); }
            ws[2 + blk * 3 + 0] = l;
            ws[2 + blk * 3 + 1] = h;
        }
        __syncthreads();
    }

    // ---- RP quantile: order stats 104858 & 104859 (1-indexed) of |ti - tj| over all L^2 pairs ----
    auto count_le = [&](float v) -> unsigned {
        float ti = t[tid];
        // first j in [0,tid] with ti - t[j] <= v  (predicate monotone: F..F T..T)
        int a = 0, bh = tid;
        while (a < bh) { int m = (a + bh) >> 1; if (ti - t[m] <= v) bh = m; else a = m + 1; }
        int jlo = a;
        // last j in [tid,L-1] with t[j] - ti <= v  (T..T F..F)
        a = tid; bh = L_ - 1;
        while (a < bh) { int m = (a + bh + 1) >> 1; if (t[m] - ti <= v) a = m; else bh = m - 1; }
        unsigned cnt = (unsigned)(a - jlo + 1);
#pragma unroll
        for (int off = 32; off; off >>= 1) cnt += __shfl_down(cnt, off);
        if (lane == 0) redc[wave] = cnt;
        __syncthreads();
        if (tid == 0) {
            unsigned s = 0;
            for (int ww = 0; ww < 16; ww++) s += redc[ww];
            redc[16] = s;
        }
        __syncthreads();
        unsigned tot = redc[16];
        __syncthreads();
        return tot;
    };

    // smallest distance strictly greater than v
    auto successor = [&](float v) -> float {
        float ti = t[tid];
        int a = 0, bh = tid;
        while (a < bh) { int m = (a + bh) >> 1; if (ti - t[m] <= v) bh = m; else a = m + 1; }
        int jlo = a;
        a = tid; bh = L_ - 1;
        while (a < bh) { int m = (a + bh + 1) >> 1; if (t[m] - ti <= v) a = m; else bh = m - 1; }
        int jhi = a;
        float s = FLT_MAX;
        if (jlo > 0)      s = fminf(s, ti - t[jlo - 1]);
        if (jhi < L_ - 1) s = fminf(s, t[jhi + 1] - ti);
#pragma unroll
        for (int off = 32; off; off >>= 1) s = fminf(s, __shfl_down(s, off));
        if (lane == 0) redf[wave] = s;
        __syncthreads();
        if (tid == 0) {
            float m2 = redf[0];
            for (int ww = 1; ww < 16; ww++) m2 = fminf(m2, redf[ww]);
            redf[16] = m2;
        }
        __syncthreads();
        float r = redf[16];
        __syncthreads();
        return r;
    };

    const unsigned k1 = 104858u, k2 = 104859u;  // floor(0.1*(L^2-1)) = 104857.5 -> ranks 104858, 104859
    float dmax = t[L_ - 1] - t[0];
    float v1;
    if (count_le(0.0f) >= k1) {
        v1 = 0.0f;
    } else {
        // bisect on uint32 bit pattern: distances are nonneg fp32 -> bits monotone.
        unsigned lob = 0u, hib = __float_as_uint(dmax);
        while (lob + 1u < hib) {
            unsigned mid = lob + ((hib - lob) >> 1);
            if (count_le(__uint_as_float(mid)) >= k1) hib = mid; else lob = mid;
        }
        v1 = __uint_as_float(hib);
    }
    float v2 = (count_le(v1) >= k2) ? v1 : successor(v1);
    float thr = v1 + (v2 - v1) * 0.5f;   // linear-interp quantile at frac 0.5
    if (tid == 0) ws[2 + blk * 3 + 2] = thr;
}

// One thread per output pixel [B, 2D, 224, 224]. 4-tap bilinear gather; GAF/RP
// evaluated only at the sampled (i,j) points.
__global__ __launch_bounds__(256) void k_out(const float* __restrict__ x,
                                             const float* __restrict__ ws,
                                             float* __restrict__ out) {
    int idx = blockIdx.x * 256 + threadIdx.x;
    if (idx >= NPIX) return;
    int ox = idx % OUT_;
    int t1 = idx / OUT_;
    int oy = t1 % OUT_;
    int t2 = t1 / OUT_;
    int c  = t2 & 15;
    int b  = t2 >> 4;

    const float scale = (float)L_ / (float)OUT_;
    float fy = (oy + 0.5f) * scale - 0.5f;   // in [1.79, 1021.22] -> no edge clamping
    float fx = (ox + 0.5f) * scale - 0.5f;
    int y0 = (int)fy; float wy = fy - (float)y0;
    int x0 = (int)fx; float wx = fx - (float)x0;

    int d = c & 7;
    const float* xb = x + b * (L_ * D_) + d;
    float r0 = xb[y0 * D_],  r1 = xb[(y0 + 1) * D_];
    float q0 = xb[x0 * D_],  q1 = xb[(x0 + 1) * D_];

    float v00, v01, v10, v11;
    if (c < 8) {
        float lo = ws[0], hi = ws[1];
        float rng  = hi - lo;
        int degen  = rng < 1e-8f;
        float inv2 = 2.0f / (rng + 1e-8f);
        float cr0 = clipnorm(r0, lo, inv2, degen), cr1 = clipnorm(r1, lo, inv2, degen);
        float cq0 = clipnorm(q0, lo, inv2, degen), cq1 = clipnorm(q1, lo, inv2, degen);
        float sr0 = sqrtf(fmaxf(0.0f, 1.0f - cr0 * cr0)), sr1 = sqrtf(fmaxf(0.0f, 1.0f - cr1 * cr1));
        float sq0 = sqrtf(fmaxf(0.0f, 1.0f - cq0 * cq0)), sq1 = sqrtf(fmaxf(0.0f, 1.0f - cq1 * cq1));
        float mn = ws[2 + (b * 8 + d) * 3 + 0];
        float mx = ws[2 + (b * 8 + d) * 3 + 1];
        float grng = mx - mn;
        int gdeg   = grng < 1e-8f;
        float ginv = 1.0f / (grng + 1e-8f);
        v00 = gdeg ? 0.0f : (cr0 * cq0 - sr0 * sq0 - mn) * ginv;
        v01 = gdeg ? 0.0f : (cr0 * cq1 - sr0 * sq1 - mn) * ginv;
        v10 = gdeg ? 0.0f : (cr1 * cq0 - sr1 * sq0 - mn) * ginv;
        v11 = gdeg ? 0.0f : (cr1 * cq1 - sr1 * sq1 - mn) * ginv;
    } else {
        float thr = ws[2 + (b * 8 + d) * 3 + 2];
        v00 = (fabsf(r0 - q0) <= thr) ? 1.0f : 0.0f;
        v01 = (fabsf(r0 - q1) <= thr) ? 1.0f : 0.0f;
        v10 = (fabsf(r1 - q0) <= thr) ? 1.0f : 0.0f;
        v11 = (fabsf(r1 - q1) <= thr) ? 1.0f : 0.0f;
    }
    float top = v00 + wx * (v01 - v00);
    float bot = v10 + wx * (v11 - v10);
    out[idx] = top + wy * (bot - top);
}

extern "C" void kernel_launch(void* const* d_in, const int* in_sizes, int n_in,
                              void* d_out, int out_size, void* d_ws, size_t ws_size,
                              hipStream_t stream) {
    const float* x = (const float*)d_in[0];
    float* out = (float*)d_out;
    float* ws  = (float*)d_ws;   // [0..1]: global lo/hi; [2 + blk*3 + {0,1,2}]: gaf mn, gaf mx, rp thr

    k_stats<<<B_ * D_, 1024, 0, stream>>>(x, ws);
    k_out<<<(NPIX + 255) / 256, 256, 0, stream>>>(x, ws, out);
}

// Round 2
// 111.698 us; speedup vs baseline: 1.2846x; 1.2846x over previous
//
#include <hip/hip_runtime.h>
#include <cfloat>
#include <math.h>

#define B_ 4
#define L_ 1024
#define D_ 8
#define OUT_ 224
#define NPIX (B_ * 2 * D_ * OUT_ * OUT_)   // 3211264
#define NT4  (NPIX / 4)                    // 802816 = 3136 * 256 exactly
#define PI_F 3.14159265358979323846f

// reference: x_norm = ((x-lo)/(rng+1e-8))*2 - 1 (or 0 if rng<1e-8), clipped to [-1+1e-6, 1-1e-6]
__device__ __forceinline__ float clipnorm(float v, float lo, float inv2, int degen) {
    float xn = degen ? -1.0f : ((v - lo) * inv2 - 1.0f);
    return fminf(fmaxf(xn, -1.0f + 1e-6f), 1.0f - 1e-6f);
}

// monotone unsigned key for float (total order); larger float -> larger key
__device__ __forceinline__ unsigned fkey(float f) {
    unsigned u = __float_as_uint(f);
    return (u & 0x80000000u) ? ~u : (u | 0x80000000u);
}
__device__ __forceinline__ float unfkey(unsigned k) {
    unsigned u = (k & 0x80000000u) ? (k ^ 0x80000000u) : ~k;
    return __uint_as_float(u);
}

// One block per (b,d). 1024 threads. Computes gaf min/max and rp quantile threshold.
__global__ __launch_bounds__(1024) void k_stats(const float* __restrict__ x,
                                                float* __restrict__ ws) {
    __shared__ float t[L_];      // sorted series values
    __shared__ float csort[L_];  // clipped-normalized at sorted positions
    __shared__ float ssort[L_];  // sqrt(1-c^2)
    __shared__ float w[L_];      // theta = acos(c), descending
    __shared__ unsigned cnt_buf[2];
    __shared__ unsigned umin_a, umax_a, umin_b, umax_b, succ_bits;

    const int tid  = threadIdx.x;
    const int lane = tid & 63;
    const int blk  = blockIdx.x;
    const int b = blk >> 3, d = blk & 7;

    if (tid == 0) {
        umin_a = 0xFFFFFFFFu; umax_a = 0u;
        umin_b = 0xFFFFFFFFu; umax_b = 0u;
        succ_bits = 0xFFFFFFFFu;
        cnt_buf[0] = 0u; cnt_buf[1] = 0u;
    }
    __syncthreads();

    // ---- global min/max over all of x (redundant per block; x = 128KB, L2-hot) ----
    {
        const float4* x4 = (const float4*)x;
        float lo = FLT_MAX, hi = -FLT_MAX;
        for (int i = tid; i < (B_ * L_ * D_) / 4; i += 1024) {
            float4 q = x4[i];
            lo = fminf(fminf(fminf(lo, q.x), q.y), fminf(q.z, q.w));
            hi = fmaxf(fmaxf(fmaxf(hi, q.x), q.y), fmaxf(q.z, q.w));
        }
#pragma unroll
        for (int off = 32; off; off >>= 1) {
            lo = fminf(lo, __shfl_down(lo, off));
            hi = fmaxf(hi, __shfl_down(hi, off));
        }
        if (lane == 0) { atomicMin(&umin_a, fkey(lo)); atomicMax(&umax_a, fkey(hi)); }
    }
    __syncthreads();
    const float glo = unfkey(umin_a), ghi = unfkey(umax_a);
    if (blk == 0 && tid == 0) { ws[0] = glo; ws[1] = ghi; }
    const float rng  = ghi - glo;
    const int degen  = rng < 1e-8f;
    const float inv2 = 2.0f / (rng + 1e-8f);

    // ---- bitonic sort of this (b,d) series, value held in register; LDS only for j>=64 ----
    float v = x[(b * L_ + tid) * D_ + d];
    for (int k = 2; k <= L_; k <<= 1) {
        bool up = ((tid & k) == 0);
        for (int j = k >> 1; j > 0; j >>= 1) {
            bool lower = ((tid & j) == 0);
            float other;
            if (j >= 64) {
                __syncthreads();
                t[tid] = v;
                __syncthreads();
                other = t[tid ^ j];
            } else {
                other = __shfl_xor(v, j);
            }
            float mn = fminf(v, other), mx = fmaxf(v, other);
            v = (lower == up) ? mn : mx;
        }
    }
    __syncthreads();
    t[tid] = v;

    // ---- derived arrays at sorted positions ----
    {
        float c = clipnorm(v, glo, inv2, degen);
        csort[tid] = c;
        ssort[tid] = sqrtf(fmaxf(0.0f, 1.0f - c * c));
        w[tid]     = acosf(c);   // descending in tid
    }
    __syncthreads();

    // ---- GAF min/max: cos(wi+wj). Extremes at sums nearest 0, pi, 2pi.
    {
        float wi = w[tid];
        int jstar = -1;
        if (wi + w[0] >= PI_F) {
            int a = 0, bh = L_ - 1;
            while (a < bh) { int m = (a + bh + 1) >> 1; if (wi + w[m] >= PI_F) a = m; else bh = m - 1; }
            jstar = a;
        }
        float ci = csort[tid], si = ssort[tid];
        float mn = FLT_MAX, mx = -FLT_MAX;
        int cands[4] = {0, L_ - 1, jstar, jstar + 1};
#pragma unroll
        for (int q = 0; q < 4; q++) {
            int j = cands[q];
            if (j >= 0 && j < L_) {
                float g = ci * csort[j] - si * ssort[j];
                mn = fminf(mn, g); mx = fmaxf(mx, g);
            }
        }
#pragma unroll
        for (int off = 32; off; off >>= 1) {
            mn = fminf(mn, __shfl_down(mn, off));
            mx = fmaxf(mx, __shfl_down(mx, off));
        }
        if (lane == 0) { atomicMin(&umin_b, fkey(mn)); atomicMax(&umax_b, fkey(mx)); }
        __syncthreads();
        if (tid == 0) {
            ws[2 + blk * 3 + 0] = unfkey(umin_b);
            ws[2 + blk * 3 + 1] = unfkey(umax_b);
        }
    }

    // ---- RP quantile: order stats 104858 & 104859 (1-indexed) of |ti - tj| over L^2 pairs ----
    // Windowed bit-bisection: per-thread count windows are nested across the v-interval,
    // so each pass's binary search is restricted to the shrinking bound range.
    int pass = 0;
    auto block_sum = [&](unsigned cnt) -> unsigned {
#pragma unroll
        for (int off = 32; off; off >>= 1) cnt += __shfl_down(cnt, off);
        if (lane == 0) atomicAdd(&cnt_buf[pass & 1], cnt);
        __syncthreads();
        unsigned tot = cnt_buf[pass & 1];
        if (tid == 0) cnt_buf[(pass + 1) & 1] = 0u;
        __syncthreads();
        pass++;
        return tot;
    };

    const float ti = v;
    // windows at v=0 (the low end): jloA = jlo(0) (upper bound for jlo), jhiA = jhi(0)
    int jloA; { int a2 = 0, b2 = tid;
        while (a2 < b2) { int m2 = (a2 + b2) >> 1; if (ti - t[m2] <= 0.0f) b2 = m2; else a2 = m2 + 1; }
        jloA = a2; }
    int jhiA; { int a2 = tid, b2 = L_ - 1;
        while (a2 < b2) { int m2 = (a2 + b2 + 1) >> 1; if (t[m2] - ti <= 0.0f) a2 = m2; else b2 = m2 - 1; }
        jhiA = a2; }
    int jloB = 0, jhiB = L_ - 1;   // windows at v=dmax (the high end)

    const unsigned k1 = 104858u, k2 = 104859u;  // floor/ceil of rank 104857.5 (1-indexed)
    const float dmax = t[L_ - 1] - t[0];

    unsigned tot0 = block_sum((unsigned)(jhiA - jloA + 1));
    float v1;
    unsigned cnt_at_v1;
    if (tot0 >= k1) {
        v1 = 0.0f; cnt_at_v1 = tot0;
        jloB = jloA; jhiB = jhiA;           // windows at v1
    } else {
        unsigned lob = 0u, hib = __float_as_uint(dmax);
        cnt_at_v1 = (unsigned)(L_ * L_);    // count at dmax
        while (hib - lob > 1u) {
            unsigned midb = lob + ((hib - lob) >> 1);
            float vm = __uint_as_float(midb);
            int jloM; { int a2 = jloB, b2 = jloA;
                while (a2 < b2) { int m2 = (a2 + b2) >> 1; if (ti - t[m2] <= vm) b2 = m2; else a2 = m2 + 1; }
                jloM = a2; }
            int jhiM; { int a2 = jhiA, b2 = jhiB;
                while (a2 < b2) { int m2 = (a2 + b2 + 1) >> 1; if (t[m2] - ti <= vm) a2 = m2; else b2 = m2 - 1; }
                jhiM = a2; }
            unsigned tot = block_sum((unsigned)(jhiM - jloM + 1));
            if (tot >= k1) { hib = midb; jloB = jloM; jhiB = jhiM; cnt_at_v1 = tot; }
            else           { lob = midb; jloA = jloM; jhiA = jhiM; }
        }
        v1 = __uint_as_float(hib);
    }

    float thr;
    if (cnt_at_v1 >= k2) {
        thr = v1;
    } else {
        // successor: smallest distance > v1; windows at v1 are (jloB, jhiB)
        float s = FLT_MAX;
        if (jloB > 0)      s = fminf(s, ti - t[jloB - 1]);
        if (jhiB < L_ - 1) s = fminf(s, t[jhiB + 1] - ti);
#pragma unroll
        for (int off = 32; off; off >>= 1) s = fminf(s, __shfl_down(s, off));
        if (lane == 0) atomicMin(&succ_bits, __float_as_uint(s));  // nonneg floats: raw bits monotone
        __syncthreads();
        float v2 = __uint_as_float(succ_bits);
        thr = v1 + (v2 - v1) * 0.5f;   // linear-interp quantile at frac 0.5
    }
    if (tid == 0) ws[2 + blk * 3 + 2] = thr;
}

// One thread per 4 consecutive output pixels; float4 store. GAF/RP evaluated only
// at the 4x4 sampled (i,j) points per pixel; L x L matrices never materialized.
__global__ __launch_bounds__(256) void k_out(const float* __restrict__ x,
                                             const float* __restrict__ ws,
                                             float4* __restrict__ out4) {
    int tix = blockIdx.x * 256 + threadIdx.x;   // grid sized exactly: no bounds check
    int pix0 = tix << 2;
    int ox0 = pix0 % OUT_;          // multiple of 4
    int t1  = pix0 / OUT_;
    int oy  = t1 % OUT_;
    int t2  = t1 / OUT_;
    int c   = t2 & 15;              // uniform per block (plane = 49 blocks exactly)
    int b   = t2 >> 4;

    const float scale = (float)L_ / (float)OUT_;
    float fy = (oy + 0.5f) * scale - 0.5f;   // in [1.79, 1021.22] -> no edge clamping
    int y0 = (int)fy; float wy = fy - (float)y0;

    int d = c & 7;
    const float* xb = x + b * (L_ * D_) + d;
    float r0 = xb[y0 * D_], r1 = xb[(y0 + 1) * D_];

    float res[4];
    if (c < 8) {
        float lo = ws[0], hi = ws[1];
        float rngg = hi - lo;
        int degen  = rngg < 1e-8f;
        float inv2 = 2.0f / (rngg + 1e-8f);
        float mn = ws[2 + (b * 8 + d) * 3 + 0];
        float mx = ws[2 + (b * 8 + d) * 3 + 1];
        float grng = mx - mn;
        int gdeg   = grng < 1e-8f;
        float ginv = 1.0f / (grng + 1e-8f);
        float cr0 = clipnorm(r0, lo, inv2, degen), cr1 = clipnorm(r1, lo, inv2, degen);
        float sr0 = sqrtf(fmaxf(0.0f, 1.0f - cr0 * cr0)), sr1 = sqrtf(fmaxf(0.0f, 1.0f - cr1 * cr1));
#pragma unroll
        for (int p = 0; p < 4; p++) {
            float fx = (ox0 + p + 0.5f) * scale - 0.5f;
            int x0 = (int)fx; float wx = fx - (float)x0;
            float q0 = xb[x0 * D_], q1 = xb[(x0 + 1) * D_];
            float cq0 = clipnorm(q0, lo, inv2, degen), cq1 = clipnorm(q1, lo, inv2, degen);
            float sq0 = sqrtf(fmaxf(0.0f, 1.0f - cq0 * cq0)), sq1 = sqrtf(fmaxf(0.0f, 1.0f - cq1 * cq1));
            float v00 = gdeg ? 0.0f : (cr0 * cq0 - sr0 * sq0 - mn) * ginv;
            float v01 = gdeg ? 0.0f : (cr0 * cq1 - sr0 * sq1 - mn) * ginv;
            float v10 = gdeg ? 0.0f : (cr1 * cq0 - sr1 * sq0 - mn) * ginv;
            float v11 = gdeg ? 0.0f : (cr1 * cq1 - sr1 * sq1 - mn) * ginv;
            float top = v00 + wx * (v01 - v00);
            float bot = v10 + wx * (v11 - v10);
            res[p] = top + wy * (bot - top);
        }
    } else {
        float thr = ws[2 + (b * 8 + d) * 3 + 2];
#pragma unroll
        for (int p = 0; p < 4; p++) {
            float fx = (ox0 + p + 0.5f) * scale - 0.5f;
            int x0 = (int)fx; float wx = fx - (float)x0;
            float q0 = xb[x0 * D_], q1 = xb[(x0 + 1) * D_];
            float v00 = (fabsf(r0 - q0) <= thr) ? 1.0f : 0.0f;
            float v01 = (fabsf(r0 - q1) <= thr) ? 1.0f : 0.0f;
            float v10 = (fabsf(r1 - q0) <= thr) ? 1.0f : 0.0f;
            float v11 = (fabsf(r1 - q1) <= thr) ? 1.0f : 0.0f;
            float top = v00 + wx * (v01 - v00);
            float bot = v10 + wx * (v11 - v10);
            res[p] = top + wy * (bot - top);
        }
    }
    out4[tix] = make_float4(res[0], res[1], res[2], res[3]);
}

extern "C" void kernel_launch(void* const* d_in, const int* in_sizes, int n_in,
                              void* d_out, int out_size, void* d_ws, size_t ws_size,
                              hipStream_t stream) {
    const float* x = (const float*)d_in[0];
    float* ws = (float*)d_ws;   // [0..1]: global lo/hi; [2 + blk*3 + {0,1,2}]: gaf mn, gaf mx, rp thr

    k_stats<<<B_ * D_, 1024, 0, stream>>>(x, ws);
    k_out<<<NT4 / 256, 256, 0, stream>>>(x, ws, (float4*)d_out);
}